// Round 1
// baseline (367.948 us; speedup 1.0000x reference)
//
#include <hip/hip_runtime.h>
#include <math.h>

#define N_NODES 200000
#define NGRAPH  512
#define HID     256
#define NTILES  (N_NODES / 16)   // 12500 exactly (200000 % 16 == 0)
#define PARTS   4

typedef __attribute__((ext_vector_type(8))) short s16x8;
typedef __attribute__((ext_vector_type(4))) float f32x4;

__device__ __forceinline__ unsigned short f2bf_rne(float f) {
  unsigned int u = __float_as_uint(f);
  return (unsigned short)((u + 0x7fffu + ((u >> 16) & 1u)) >> 16);
}
__device__ __forceinline__ unsigned int pack2_bf16_rne(float a, float b) {
  unsigned int ua = __float_as_uint(a), ub = __float_as_uint(b);
  unsigned int ra = (ua + 0x7fffu + ((ua >> 16) & 1u)) >> 16;
  unsigned int rb = (ub + 0x7fffu + ((ub >> 16) & 1u)) & 0xffff0000u;
  return ra | rb;
}
__device__ __forceinline__ int lower_bound_batch(const int* __restrict__ batch, int target) {
  int lo = 0, hi = N_NODES;
  while (lo < hi) { int mid = (lo + hi) >> 1; if (batch[mid] < target) lo = mid + 1; else hi = mid; }
  return lo;
}
__device__ __forceinline__ f32x4 vmax4(f32x4 a, f32x4 b) {
  return (f32x4){fmaxf(a[0], b[0]), fmaxf(a[1], b[1]), fmaxf(a[2], b[2]), fmaxf(a[3], b[3])};
}

// ---------------------------------------------------------------------------
// Kernel 1: gate GEMM only. g[i] = relu(x_i @ w1 + b1) @ w2 + b2.
// No segment logic, no pool tail -> short per-tile chain, 16 waves/CU.
// Fragment/epilogue math copied verbatim from the validated fused kernel.
// ---------------------------------------------------------------------------
__global__ __launch_bounds__(256, 2) void gate_kernel(
    const float* __restrict__ x, const float* __restrict__ w1,
    const float* __restrict__ b1, const float* __restrict__ w2,
    const float* __restrict__ b2, float* __restrict__ g)
{
  __shared__ __align__(16) short w1T[64 * 264];  // bf16 w1^T [n][k], pitch 264
  const int tid = threadIdx.x;
  const int w = tid >> 6, lane = tid & 63, q = lane >> 4, c = lane & 15;

  for (int i = tid; i < 256 * 64; i += 256) {  // i = k*64 + n, coalesced
    int k = i >> 6, n = i & 63;
    w1T[n * 264 + k] = (short)f2bf_rne(w1[i]);
  }
  __syncthreads();

  float b1v[4], w2v[4];
#pragma unroll
  for (int nt = 0; nt < 4; ++nt) { b1v[nt] = b1[nt * 16 + c]; w2v[nt] = w2[nt * 16 + c]; }
  const float b2v = b2[0];

  const int tstride = gridDim.x << 2;
  for (int t = (blockIdx.x << 2) + w; t < NTILES; t += tstride) {
    const int r0 = t << 4;
    const float* ap = x + (size_t)(r0 + c) * HID + q * 8;
    union { s16x8 v; unsigned int u[4]; } ah[8];
#pragma unroll
    for (int half = 0; half < 2; ++half) {   // two 4-kt halves: <=32 load VGPRs
      float4 t0[4], t1[4];
#pragma unroll
      for (int kk = 0; kk < 4; ++kk) {
        int kt = half * 4 + kk;
        t0[kk] = *(const float4*)(ap + kt * 32);
        t1[kk] = *(const float4*)(ap + kt * 32 + 4);
      }
#pragma unroll
      for (int kk = 0; kk < 4; ++kk) {
        int kt = half * 4 + kk;
        ah[kt].u[0] = pack2_bf16_rne(t0[kk].x, t0[kk].y);
        ah[kt].u[1] = pack2_bf16_rne(t0[kk].z, t0[kk].w);
        ah[kt].u[2] = pack2_bf16_rne(t1[kk].x, t1[kk].y);
        ah[kt].u[3] = pack2_bf16_rne(t1[kk].z, t1[kk].w);
      }
    }

    f32x4 acc[4];
#pragma unroll
    for (int nt = 0; nt < 4; ++nt) acc[nt] = (f32x4){0.f, 0.f, 0.f, 0.f};
#pragma unroll
    for (int kt = 0; kt < 8; ++kt) {
#pragma unroll
      for (int nt = 0; nt < 4; ++nt) {
        s16x8 bh = *(const s16x8*)&w1T[(nt * 16 + c) * 264 + kt * 32 + q * 8];
        acc[nt] = __builtin_amdgcn_mfma_f32_16x16x32_bf16(ah[kt].v, bh, acc[nt], 0, 0, 0);
      }
    }

    // D[row=4q+r][col=nt*16+c]; butterfly over c -> gate(row 4q+r) uniform in quad
    float gr[4];
#pragma unroll
    for (int r = 0; r < 4; ++r) {
      float sv = 0.f;
#pragma unroll
      for (int nt = 0; nt < 4; ++nt) {
        float h = acc[nt][r] + b1v[nt];
        h = h > 0.f ? h : 0.f;
        sv += h * w2v[nt];
      }
      sv += __shfl_xor(sv, 1, 64);
      sv += __shfl_xor(sv, 2, 64);
      sv += __shfl_xor(sv, 4, 64);
      sv += __shfl_xor(sv, 8, 64);
      gr[r] = sv + b2v;
    }
    if (c == 0) {
      float4 o = make_float4(gr[0], gr[1], gr[2], gr[3]);
      *(float4*)(g + r0 + q * 4) = o;   // rows r0+4q .. r0+4q+3, 16B aligned
    }
  }
}

// ---------------------------------------------------------------------------
// Kernel 2: per-segment softmax stats over g, then FINAL per-node weights:
// wgt[i] = exp(g[i]-m)/max(den,1e-16). Reads 0.8 MB x3 -> ~3 us.
// ---------------------------------------------------------------------------
__global__ __launch_bounds__(256) void seg_softmax(
    const float* __restrict__ g, const int* __restrict__ batch,
    float* __restrict__ wgt)
{
  __shared__ int sb[2];
  __shared__ float red[4];
  const int tid = threadIdx.x;
  const int w = tid >> 6, lane = tid & 63;
  if (tid < 2) sb[tid] = lower_bound_batch(batch, (int)blockIdx.x + tid);
  __syncthreads();
  const int s0 = sb[0], e0 = sb[1];

  float m = -INFINITY;
  for (int i = s0 + tid; i < e0; i += 256) m = fmaxf(m, g[i]);
#pragma unroll
  for (int off = 32; off > 0; off >>= 1) m = fmaxf(m, __shfl_xor(m, off, 64));
  if (lane == 0) red[w] = m;
  __syncthreads();
  m = fmaxf(fmaxf(red[0], red[1]), fmaxf(red[2], red[3]));
  __syncthreads();

  float den = 0.f;
  for (int i = s0 + tid; i < e0; i += 256) den += __expf(g[i] - m);
#pragma unroll
  for (int off = 32; off > 0; off >>= 1) den += __shfl_xor(den, off, 64);
  if (lane == 0) red[w] = den;
  __syncthreads();
  den = red[0] + red[1] + red[2] + red[3];

  const float inv = 1.f / fmaxf(den, 1e-16f);
  for (int i = s0 + tid; i < e0; i += 256) wgt[i] = __expf(g[i] - m) * inv;
}

// ---------------------------------------------------------------------------
// Kernel 3: streaming pool. Block = (segment, quarter). Lane owns 4 columns,
// waves stride rows. Weights are global/final -> no exp, no shuffles, no
// rescale: pure float4 load + fma/max with 4 loads in flight. x is L3-hot.
// ---------------------------------------------------------------------------
__global__ __launch_bounds__(256, 8) void pool_pass(
    const float* __restrict__ x, const int* __restrict__ batch,
    const float* __restrict__ wgt, float* __restrict__ pbuf)
{
  __shared__ int sb[2];
  __shared__ __align__(16) float scr[12 * 256];
  const int tid = threadIdx.x;
  const int w = tid >> 6, lane = tid & 63;
  const int seg = blockIdx.x >> 2, p = blockIdx.x & 3;

  if (tid < 2) sb[tid] = lower_bound_batch(batch, seg + tid);
  __syncthreads();
  const int s0 = sb[0], len = sb[1] - s0;
  const int ps = s0 + ((len * p) >> 2);
  const int pe = s0 + ((len * (p + 1)) >> 2);

  f32x4 sum = (f32x4){0.f, 0.f, 0.f, 0.f};
  f32x4 at  = (f32x4){0.f, 0.f, 0.f, 0.f};
  f32x4 mx  = (f32x4){-INFINITY, -INFINITY, -INFINITY, -INFINITY};

  const float* xp = x + lane * 4;
  int r = ps + w;
  for (; r + 12 < pe; r += 16) {     // 4 rows (stride 4) per iteration
    float4 v0 = *(const float4*)(xp + (size_t)(r     ) * HID);
    float4 v1 = *(const float4*)(xp + (size_t)(r +  4) * HID);
    float4 v2 = *(const float4*)(xp + (size_t)(r +  8) * HID);
    float4 v3 = *(const float4*)(xp + (size_t)(r + 12) * HID);
    float w0 = wgt[r], w1v = wgt[r + 4], w2v = wgt[r + 8], w3v = wgt[r + 12];
    f32x4 f0 = (f32x4){v0.x, v0.y, v0.z, v0.w};
    f32x4 f1 = (f32x4){v1.x, v1.y, v1.z, v1.w};
    f32x4 f2 = (f32x4){v2.x, v2.y, v2.z, v2.w};
    f32x4 f3 = (f32x4){v3.x, v3.y, v3.z, v3.w};
    sum = sum + ((f0 + f1) + (f2 + f3));
    mx = vmax4(mx, vmax4(vmax4(f0, f1), vmax4(f2, f3)));
#pragma unroll
    for (int j = 0; j < 4; ++j) {
      float a = fmaf(w0, f0[j], at[j]);
      a = fmaf(w1v, f1[j], a);
      a = fmaf(w2v, f2[j], a);
      at[j] = fmaf(w3v, f3[j], a);
    }
  }
  for (; r < pe; r += 4) {
    float4 v = *(const float4*)(xp + (size_t)r * HID);
    float wr = wgt[r];
    f32x4 f = (f32x4){v.x, v.y, v.z, v.w};
    sum = sum + f;
    mx = vmax4(mx, f);
#pragma unroll
    for (int j = 0; j < 4; ++j) at[j] = fmaf(wr, f[j], at[j]);
  }

  // cross-wave merge (no softmax rescale needed: weights are final)
  {
    float* p0 = scr + (w * 3 + 0) * 256;
    float* p1 = scr + (w * 3 + 1) * 256;
    float* p2 = scr + (w * 3 + 2) * 256;
    *(f32x4*)&p0[lane * 4] = sum;
    *(f32x4*)&p1[lane * 4] = mx;
    *(f32x4*)&p2[lane * 4] = at;
  }
  __syncthreads();
  {
    const int f = tid;
    float S = 0.f, MX = -INFINITY, A = 0.f;
#pragma unroll
    for (int ww = 0; ww < 4; ++ww) {
      S += scr[(ww * 3 + 0) * 256 + f];
      MX = fmaxf(MX, scr[(ww * 3 + 1) * 256 + f]);
      A += scr[(ww * 3 + 2) * 256 + f];
    }
    float* pr = pbuf + (size_t)blockIdx.x * 772;
    pr[f] = S; pr[256 + f] = MX; pr[512 + f] = A;
    if (tid == 0) pr[768] = (float)(pe - ps);
  }
}

// ---------------------------------------------------------------------------
// Kernel 4: merge PARTS partials per segment -> z (512 x 768 fp32).
// ---------------------------------------------------------------------------
__global__ __launch_bounds__(256) void pool_merge2(
    const float* __restrict__ pbuf, float* __restrict__ zbuf)
{
  const int seg = blockIdx.x, f = threadIdx.x;
  float S = 0.f, A = 0.f, MX = -INFINITY, cnt = 0.f;
#pragma unroll
  for (int pp = 0; pp < PARTS; ++pp) {
    const float* pr = pbuf + (size_t)(seg * PARTS + pp) * 772;
    S += pr[f];
    MX = fmaxf(MX, pr[256 + f]);
    A += pr[512 + f];
    cnt += pr[768];
  }
  float* zr = zbuf + (size_t)seg * 768;
  zr[f]       = S / fmaxf(cnt, 1.f);
  zr[256 + f] = (cnt > 0.f) ? MX : 0.f;
  zr[512 + f] = A;            // weights already include 1/den
}

// ---------------------------------------------------------------------------
// Kernel 5: y = z @ wp + bp, LayerNorm, fp32 out. (unchanged)
// ---------------------------------------------------------------------------
__global__ __launch_bounds__(256) void head_ln(
    const float* __restrict__ zbuf, const float* __restrict__ wp,
    const float* __restrict__ bp, const float* __restrict__ gam,
    const float* __restrict__ bet, float* __restrict__ out)
{
  const int g = blockIdx.x;
  const int tid = threadIdx.x;
  const int w = tid >> 6, lane = tid & 63;
  __shared__ float z[768];
  __shared__ __align__(16) float part[4][256];
  __shared__ float red[256];

  for (int i = tid; i < 768; i += 256) z[i] = zbuf[(size_t)g * 768 + i];
  __syncthreads();

  f32x4 acc = (f32x4){0.f, 0.f, 0.f, 0.f};
  const float4* wp4 = (const float4*)wp;
  const int k0 = w * 192;
#pragma unroll 8
  for (int k = k0; k < k0 + 192; ++k) {
    float4 wv = wp4[(size_t)k * 64 + lane];
    float zk = z[k];
    acc[0] = fmaf(zk, wv.x, acc[0]);
    acc[1] = fmaf(zk, wv.y, acc[1]);
    acc[2] = fmaf(zk, wv.z, acc[2]);
    acc[3] = fmaf(zk, wv.w, acc[3]);
  }
  *(f32x4*)&part[w][lane * 4] = acc;
  __syncthreads();

  const int t = tid;
  float y = bp[t] + part[0][t] + part[1][t] + part[2][t] + part[3][t];

  red[t] = y;
  __syncthreads();
  for (int wd = 128; wd > 0; wd >>= 1) {
    if (t < wd) red[t] += red[t + wd];
    __syncthreads();
  }
  const float mu = red[0] * (1.f / 256.f);
  __syncthreads();
  float d = y - mu;
  red[t] = d * d;
  __syncthreads();
  for (int wd = 128; wd > 0; wd >>= 1) {
    if (t < wd) red[t] += red[t + wd];
    __syncthreads();
  }
  const float var = red[0] * (1.f / 256.f);
  const float is = rsqrtf(var + 1e-5f);
  out[(size_t)g * 256 + t] = fmaf(d * is, gam[t], bet[t]);
}

// ---------------------------------------------------------------------------
extern "C" void kernel_launch(void* const* d_in, const int* in_sizes, int n_in,
                              void* d_out, int out_size, void* d_ws, size_t ws_size,
                              hipStream_t stream) {
  const float* x   = (const float*)d_in[0];
  const int*   bat = (const int*)d_in[1];
  const float* w1  = (const float*)d_in[2];
  const float* b1  = (const float*)d_in[3];
  const float* w2  = (const float*)d_in[4];
  const float* b2  = (const float*)d_in[5];
  const float* wp  = (const float*)d_in[6];
  const float* bp  = (const float*)d_in[7];
  const float* gam = (const float*)d_in[8];
  const float* bet = (const float*)d_in[9];
  float* out = (float*)d_out;

  // ws layout: g (200000 f32) | wgt (200000 f32) | pbuf (2048*772 f32) | zbuf
  float* gbuf = (float*)d_ws;
  float* wgt  = gbuf + N_NODES;
  float* pbuf = wgt + N_NODES;
  float* zbuf = pbuf + (size_t)NGRAPH * PARTS * 772;

  hipLaunchKernelGGL(gate_kernel, dim3(1024), dim3(256), 0, stream,
                     x, w1, b1, w2, b2, gbuf);
  hipLaunchKernelGGL(seg_softmax, dim3(NGRAPH), dim3(256), 0, stream,
                     gbuf, bat, wgt);
  hipLaunchKernelGGL(pool_pass, dim3(NGRAPH * PARTS), dim3(256), 0, stream,
                     x, bat, wgt, pbuf);
  hipLaunchKernelGGL(pool_merge2, dim3(NGRAPH), dim3(256), 0, stream, pbuf, zbuf);
  hipLaunchKernelGGL(head_ln, dim3(NGRAPH), dim3(256), 0, stream,
                     zbuf, wp, bp, gam, bet, out);
}